// Round 1
// baseline (85.165 us; speedup 1.0000x reference)
//
#include <hip/hip_runtime.h>

#define MARGIN 0.2f
#define EPSC 1e-6f

__device__ inline void acc8(const float4& av, const float4& pv, const float4& nv,
                            float& sap, float& san) {
    float d;
    d = av.x - pv.x + EPSC; sap += d * d;
    d = av.y - pv.y + EPSC; sap += d * d;
    d = av.z - pv.z + EPSC; sap += d * d;
    d = av.w - pv.w + EPSC; sap += d * d;
    d = av.x - nv.x + EPSC; san += d * d;
    d = av.y - nv.y + EPSC; san += d * d;
    d = av.z - nv.z + EPSC; san += d * d;
    d = av.w - nv.w + EPSC; san += d * d;
}

// One 256-wide scan step: lane holds j = j0 + lane*4 + s (s=0..3).
// Updates pos/neg (first-j semantics) for one row's (li, myidx).
__device__ inline void scan4(const int4& lj, const int4& xj, int li, int myidx,
                             int j0, int& pos, int& neg) {
    if (pos < 0) {
        int m = ((lj.x == li && xj.x != myidx) ? 1 : 0)
              | ((lj.y == li && xj.y != myidx) ? 2 : 0)
              | ((lj.z == li && xj.z != myidx) ? 4 : 0)
              | ((lj.w == li && xj.w != myidx) ? 8 : 0);
        unsigned long long b = __ballot(m != 0);
        if (b) {
            int L  = __ffsll(b) - 1;
            int mL = __shfl(m, L, 64);
            pos = j0 + L * 4 + (__ffs(mL) - 1);
        }
    }
    if (neg < 0) {
        int m = ((lj.x != li) ? 1 : 0) | ((lj.y != li) ? 2 : 0)
              | ((lj.z != li) ? 4 : 0) | ((lj.w != li) ? 8 : 0);
        unsigned long long b = __ballot(m != 0);
        if (b) {
            int L  = __ffsll(b) - 1;
            int mL = __shfl(m, L, 64);
            neg = j0 + L * 4 + (__ffs(mL) - 1);
        }
    }
}

// Generic 64-wide per-row scan (B not a multiple of 256).
__device__ inline void mine_row_64(const int* __restrict__ label,
                                   const int* __restrict__ zidx, int B, int lane,
                                   int li, int myidx, int& pos, int& neg) {
    pos = -1; neg = -1;
    for (int j0 = 0; j0 < B && (pos < 0 || neg < 0); j0 += 64) {
        int j = j0 + lane;
        bool inb = j < B;
        int lj = 0, xj = 0;
        if (inb) { lj = label[j]; xj = zidx[j]; }
        unsigned long long pb = __ballot(inb && lj == li && xj != myidx);
        unsigned long long nb = __ballot(inb && lj != li);
        if (pos < 0 && pb) pos = j0 + __ffsll(pb) - 1;
        if (neg < 0 && nb) neg = j0 + __ffsll(nb) - 1;
    }
}

// Cold path: ALL labels identical -> reference relabels rows [0,k) to -1.
// Effective-label structure is analytic: groups are [0,k) and [k,B).
__device__ inline void mine_allsame(const int* __restrict__ zidx, int B, int lane,
                                    int i, int myidx, int& pos, int& neg) {
    int k = B / 100; if (k < 2) k = 2;
    int kk = k < B ? k : B;
    int lo, hi;
    if (i < kk) { lo = 0;  hi = kk; neg = (kk < B) ? kk : -1; }
    else        { lo = kk; hi = B;  neg = 0; }
    pos = -1;
    for (int j0 = lo; j0 < hi && pos < 0; j0 += 64) {
        int j = j0 + lane;
        bool ok = (j < hi) && (zidx[j] != myidx);
        unsigned long long b = __ballot(ok);
        if (b) pos = j0 + __ffsll(b) - 1;
    }
}

// -------- Kernel 0: mining only, ONE wave per row --------
// Pure L2-broadcast label/zidx scans; writes (pos,neg) per row to ws.
// Keeps mining's dependent ballot/branch chain OFF the distance kernel's
// critical path and out of its register budget.
__global__ __launch_bounds__(256) void mine_kernel(
    const int* __restrict__ label, const int* __restrict__ zidx,
    int B, int2* __restrict__ pn)
{
    const int wave = threadIdx.x >> 6;
    const int lane = threadIdx.x & 63;
    const int i = blockIdx.x * 4 + wave;
    if (i >= B) return;

    const int li = label[i];
    const int myidx = zidx[i];
    int pos = -1, neg = -1;

    if ((B & 255) == 0) {
        for (int j0 = 0; j0 < B && (pos < 0 || neg < 0); j0 += 256) {
            const int base = j0 + lane * 4;
            int4 lj = *(const int4*)(label + base);
            int4 xj = *(const int4*)(zidx + base);
            scan4(lj, xj, li, myidx, j0, pos, neg);
        }
    } else {
        mine_row_64(label, zidx, B, lane, li, myidx, pos, neg);
    }
    if (neg < 0)  // no different label anywhere -> all-same cold path
        mine_allsame(zidx, B, lane, i, myidx, pos, neg);

    if (lane == 0) pn[i] = make_int2(pos, neg);
}

// -------- Kernel 1: distances only, TWO rows per wave --------
// Same block/row mapping and identical FP accumulation order as the
// previously passing fused kernel (bit-identical partials), but now a pure
// streaming kernel: 12 float4 loads per row issued immediately, no mining.
__global__ __launch_bounds__(256) void dist_kernel(
    const float* __restrict__ z, const int2* __restrict__ pn,
    int B, int C, float2* __restrict__ g_part)
{
    const int wave = threadIdx.x >> 6;
    const int lane = threadIdx.x & 63;
    const int ia = blockIdx.x * 8 + wave * 2;
    const int ib = ia + 1;
    const bool hasA = ia < B, hasB = ib < B;
    const bool c1024 = (C == 1024);

    float lsum = 0.f, lcnt = 0.f;

    int2 pnA = hasA ? pn[ia] : make_int2(0, 0);
    int2 pnB = hasB ? pn[ib] : make_int2(0, 0);

    // ---- row A ----
    if (hasA) {
        const int pi = pnA.x < 0 ? 0 : pnA.x;    // argmax of all-False = 0
        const int ni = pnA.y < 0 ? 0 : pnA.y;
        const float4* a = (const float4*)(z + (size_t)ia * C) + lane;
        const float4* p = (const float4*)(z + (size_t)pi * C) + lane;
        const float4* n = (const float4*)(z + (size_t)ni * C) + lane;
        float sap = 0.f, san = 0.f;
        if (c1024) {
            float4 A0 = a[0], A1 = a[64], A2 = a[128], A3 = a[192];
            float4 p0 = p[0], p1 = p[64], p2 = p[128], p3 = p[192];
            float4 n0 = n[0], n1 = n[64], n2 = n[128], n3 = n[192];
            acc8(A0, p0, n0, sap, san); acc8(A1, p1, n1, sap, san);
            acc8(A2, p2, n2, sap, san); acc8(A3, p3, n3, sap, san);
        } else {
            const int nk = C >> 8;
            for (int kk = 0; kk < nk; ++kk)
                acc8(a[kk * 64], p[kk * 64], n[kk * 64], sap, san);
            for (int c = (nk << 8) + lane; c < C; c += 64) {
                float av = z[(size_t)ia * C + c];
                float pv = z[(size_t)pi * C + c];
                float nv = z[(size_t)ni * C + c];
                float d = av - pv + EPSC; sap += d * d;
                d = av - nv + EPSC; san += d * d;
            }
        }
        for (int off = 32; off; off >>= 1) {
            sap += __shfl_xor(sap, off, 64);
            san += __shfl_xor(san, off, 64);
        }
        if (lane == 0 && pnA.x >= 0 && pnA.y >= 0) {
            lsum += fmaxf(sqrtf(sap) - sqrtf(san) + MARGIN, 0.f);
            lcnt += 1.f;
        }
    }

    // ---- row B ----
    if (hasB) {
        const int pi = pnB.x < 0 ? 0 : pnB.x;
        const int ni = pnB.y < 0 ? 0 : pnB.y;
        const float4* a = (const float4*)(z + (size_t)ib * C) + lane;
        const float4* p = (const float4*)(z + (size_t)pi * C) + lane;
        const float4* n = (const float4*)(z + (size_t)ni * C) + lane;
        float sap = 0.f, san = 0.f;
        if (c1024) {
            float4 A0 = a[0], A1 = a[64], A2 = a[128], A3 = a[192];
            float4 p0 = p[0], p1 = p[64], p2 = p[128], p3 = p[192];
            float4 n0 = n[0], n1 = n[64], n2 = n[128], n3 = n[192];
            acc8(A0, p0, n0, sap, san); acc8(A1, p1, n1, sap, san);
            acc8(A2, p2, n2, sap, san); acc8(A3, p3, n3, sap, san);
        } else {
            const int nk = C >> 8;
            for (int kk = 0; kk < nk; ++kk)
                acc8(a[kk * 64], p[kk * 64], n[kk * 64], sap, san);
            for (int c = (nk << 8) + lane; c < C; c += 64) {
                float av = z[(size_t)ib * C + c];
                float pv = z[(size_t)pi * C + c];
                float nv = z[(size_t)ni * C + c];
                float d = av - pv + EPSC; sap += d * d;
                d = av - nv + EPSC; san += d * d;
            }
        }
        for (int off = 32; off; off >>= 1) {
            sap += __shfl_xor(sap, off, 64);
            san += __shfl_xor(san, off, 64);
        }
        if (lane == 0 && pnB.x >= 0 && pnB.y >= 0) {
            lsum += fmaxf(sqrtf(sap) - sqrtf(san) + MARGIN, 0.f);
            lcnt += 1.f;
        }
    }

    __shared__ float s_sum[4], s_cnt[4];
    if (lane == 0) { s_sum[wave] = lsum; s_cnt[wave] = lcnt; }
    __syncthreads();
    if (threadIdx.x == 0) {
        float bs = 0.f, bc = 0.f;
        for (int w = 0; w < 4; ++w) { bs += s_sum[w]; bc += s_cnt[w]; }
        g_part[blockIdx.x] = make_float2(bs, bc);   // uncontended, no ws-init needed
    }
}

// -------- Kernel 2: reduce partials, write loss (unchanged) --------
__global__ __launch_bounds__(1024) void final_kernel(
    const float2* __restrict__ g_part, int nb, float* __restrict__ out)
{
    const int t = threadIdx.x;
    float s = 0.f, c = 0.f;
    for (int idx = t; idx < nb; idx += blockDim.x) {
        float2 v = g_part[idx];
        s += v.x; c += v.y;
    }
    for (int off = 32; off; off >>= 1) {
        s += __shfl_xor(s, off, 64);
        c += __shfl_xor(c, off, 64);
    }
    __shared__ float s_s[16], s_c[16];
    const int wave = t >> 6, lane = t & 63;
    if (lane == 0) { s_s[wave] = s; s_c[wave] = c; }
    __syncthreads();
    if (t == 0) {
        float ts = 0.f, tc = 0.f;
        const int nw = blockDim.x >> 6;
        for (int w = 0; w < nw; ++w) { ts += s_s[w]; tc += s_c[w]; }
        out[0] = (tc > 0.f) ? ts / tc : 0.f;
    }
}

extern "C" void kernel_launch(void* const* d_in, const int* in_sizes, int n_in,
                              void* d_out, int out_size, void* d_ws, size_t ws_size,
                              hipStream_t stream) {
    const int*   z_label = (const int*)d_in[0];
    const int*   z_idx   = (const int*)d_in[1];
    const float* z       = (const float*)d_in[2];
    const int B = in_sizes[0];
    const int C = in_sizes[2] / B;
    float* out = (float*)d_out;

    const int nblk = (B + 7) / 8;       // 2 rows per wave, 4 waves/block
    float2* g_part = (float2*)d_ws;
    // pn array lives after g_part, 256B-aligned
    size_t pn_off = ((size_t)nblk * sizeof(float2) + 255) & ~(size_t)255;
    int2* pn = (int2*)((char*)d_ws + pn_off);

    mine_kernel<<<(B + 3) / 4, 256, 0, stream>>>(z_label, z_idx, B, pn);
    dist_kernel<<<nblk, 256, 0, stream>>>(z, pn, B, C, g_part);
    final_kernel<<<1, 1024, 0, stream>>>(g_part, nblk, out);
}

// Round 2
// 84.948 us; speedup vs baseline: 1.0026x; 1.0026x over previous
//
#include <hip/hip_runtime.h>

#define MARGIN 0.2f
#define EPSC 1e-6f

__device__ inline void acc8(const float4& av, const float4& pv, const float4& nv,
                            float& sap, float& san) {
    float d;
    d = av.x - pv.x + EPSC; sap += d * d;
    d = av.y - pv.y + EPSC; sap += d * d;
    d = av.z - pv.z + EPSC; sap += d * d;
    d = av.w - pv.w + EPSC; sap += d * d;
    d = av.x - nv.x + EPSC; san += d * d;
    d = av.y - nv.y + EPSC; san += d * d;
    d = av.z - nv.z + EPSC; san += d * d;
    d = av.w - nv.w + EPSC; san += d * d;
}

// One 256-wide scan step: lane holds j = j0 + lane*4 + s (s=0..3).
__device__ inline void scan4(const int4& lj, const int4& xj, int li, int myidx,
                             int j0, int& pos, int& neg) {
    if (pos < 0) {
        int m = ((lj.x == li && xj.x != myidx) ? 1 : 0)
              | ((lj.y == li && xj.y != myidx) ? 2 : 0)
              | ((lj.z == li && xj.z != myidx) ? 4 : 0)
              | ((lj.w == li && xj.w != myidx) ? 8 : 0);
        unsigned long long b = __ballot(m != 0);
        if (b) {
            int L  = __ffsll(b) - 1;
            int mL = __shfl(m, L, 64);
            pos = j0 + L * 4 + (__ffs(mL) - 1);
        }
    }
    if (neg < 0) {
        int m = ((lj.x != li) ? 1 : 0) | ((lj.y != li) ? 2 : 0)
              | ((lj.z != li) ? 4 : 0) | ((lj.w != li) ? 8 : 0);
        unsigned long long b = __ballot(m != 0);
        if (b) {
            int L  = __ffsll(b) - 1;
            int mL = __shfl(m, L, 64);
            neg = j0 + L * 4 + (__ffs(mL) - 1);
        }
    }
}

// Generic 64-wide per-row scan (B not a multiple of 256).
__device__ inline void mine_row_64(const int* __restrict__ label,
                                   const int* __restrict__ zidx, int B, int lane,
                                   int li, int myidx, int& pos, int& neg) {
    pos = -1; neg = -1;
    for (int j0 = 0; j0 < B && (pos < 0 || neg < 0); j0 += 64) {
        int j = j0 + lane;
        bool inb = j < B;
        int lj = 0, xj = 0;
        if (inb) { lj = label[j]; xj = zidx[j]; }
        unsigned long long pb = __ballot(inb && lj == li && xj != myidx);
        unsigned long long nb = __ballot(inb && lj != li);
        if (pos < 0 && pb) pos = j0 + __ffsll(pb) - 1;
        if (neg < 0 && nb) neg = j0 + __ffsll(nb) - 1;
    }
}

// Cold path: ALL labels identical -> reference relabels rows [0,k) to -1.
__device__ inline void mine_allsame(const int* __restrict__ zidx, int B, int lane,
                                    int i, int myidx, int& pos, int& neg) {
    int k = B / 100; if (k < 2) k = 2;
    int kk = k < B ? k : B;
    int lo, hi;
    if (i < kk) { lo = 0;  hi = kk; neg = (kk < B) ? kk : -1; }
    else        { lo = kk; hi = B;  neg = 0; }
    pos = -1;
    for (int j0 = lo; j0 < hi && pos < 0; j0 += 64) {
        int j = j0 + lane;
        bool ok = (j < hi) && (zidx[j] != myidx);
        unsigned long long b = __ballot(ok);
        if (b) pos = j0 + __ffsll(b) - 1;
    }
}

// -------- Kernel 0: mining only, ONE wave per row --------
__global__ __launch_bounds__(256) void mine_kernel(
    const int* __restrict__ label, const int* __restrict__ zidx,
    int B, int2* __restrict__ pn)
{
    const int wave = threadIdx.x >> 6;
    const int lane = threadIdx.x & 63;
    const int i = blockIdx.x * 4 + wave;
    if (i >= B) return;

    const int li = label[i];
    const int myidx = zidx[i];
    int pos = -1, neg = -1;

    if ((B & 255) == 0) {
        for (int j0 = 0; j0 < B && (pos < 0 || neg < 0); j0 += 256) {
            const int base = j0 + lane * 4;
            int4 lj = *(const int4*)(label + base);
            int4 xj = *(const int4*)(zidx + base);
            scan4(lj, xj, li, myidx, j0, pos, neg);
        }
    } else {
        mine_row_64(label, zidx, B, lane, li, myidx, pos, neg);
    }
    if (neg < 0)
        mine_allsame(zidx, B, lane, i, myidx, pos, neg);

    if (lane == 0) pn[i] = make_int2(pos, neg);
}

// Per-row generic (non-1024) distance path, FP order identical to before.
__device__ inline void row_generic(const float* __restrict__ z, int i, int pi,
                                   int ni, int C, int lane,
                                   float& lsum, float& lcnt, bool valid) {
    const float4* a = (const float4*)(z + (size_t)i  * C) + lane;
    const float4* p = (const float4*)(z + (size_t)pi * C) + lane;
    const float4* n = (const float4*)(z + (size_t)ni * C) + lane;
    float sap = 0.f, san = 0.f;
    const int nk = C >> 8;
    for (int kk = 0; kk < nk; ++kk)
        acc8(a[kk * 64], p[kk * 64], n[kk * 64], sap, san);
    for (int c = (nk << 8) + lane; c < C; c += 64) {
        float av = z[(size_t)i  * C + c];
        float pv = z[(size_t)pi * C + c];
        float nv = z[(size_t)ni * C + c];
        float d = av - pv + EPSC; sap += d * d;
        d = av - nv + EPSC; san += d * d;
    }
    for (int off = 32; off; off >>= 1) {
        sap += __shfl_xor(sap, off, 64);
        san += __shfl_xor(san, off, 64);
    }
    if (lane == 0 && valid) {
        lsum += fmaxf(sqrtf(sap) - sqrtf(san) + MARGIN, 0.f);
        lcnt += 1.f;
    }
}

// -------- Kernel 1: distances, TWO rows per wave, ALL 24 loads in flight ----
// Same wave->row map and identical FP accumulation order as before
// (bit-identical partials). Difference: both rows' a/p/n float4 loads are
// issued before any arithmetic, so the wave exposes ONE gather latency
// instead of two serialized ones.
__global__ __launch_bounds__(256) void dist_kernel(
    const float* __restrict__ z, const int2* __restrict__ pn,
    int B, int C, float2* __restrict__ g_part)
{
    const int wave = threadIdx.x >> 6;
    const int lane = threadIdx.x & 63;
    const int ia = blockIdx.x * 8 + wave * 2;
    const int ib = ia + 1;
    const bool hasA = ia < B, hasB = ib < B;

    float lsum = 0.f, lcnt = 0.f;

    int2 pnA = hasA ? pn[ia] : make_int2(0, 0);
    int2 pnB = hasB ? pn[ib] : make_int2(0, 0);

    if (C == 1024 && hasA && hasB) {
        const int piA = pnA.x < 0 ? 0 : pnA.x;
        const int niA = pnA.y < 0 ? 0 : pnA.y;
        const int piB = pnB.x < 0 ? 0 : pnB.x;
        const int niB = pnB.y < 0 ? 0 : pnB.y;
        const float4* aA = (const float4*)(z + (size_t)ia  * 1024) + lane;
        const float4* pA = (const float4*)(z + (size_t)piA * 1024) + lane;
        const float4* nA = (const float4*)(z + (size_t)niA * 1024) + lane;
        const float4* aB = (const float4*)(z + (size_t)ib  * 1024) + lane;
        const float4* pB = (const float4*)(z + (size_t)piB * 1024) + lane;
        const float4* nB = (const float4*)(z + (size_t)niB * 1024) + lane;

        // issue everything: 24 float4 loads, no arithmetic in between
        float4 A0 = aA[0], A1 = aA[64], A2 = aA[128], A3 = aA[192];
        float4 PA0 = pA[0], PA1 = pA[64], PA2 = pA[128], PA3 = pA[192];
        float4 NA0 = nA[0], NA1 = nA[64], NA2 = nA[128], NA3 = nA[192];
        float4 B0 = aB[0], B1 = aB[64], B2 = aB[128], B3 = aB[192];
        float4 PB0 = pB[0], PB1 = pB[64], PB2 = pB[128], PB3 = pB[192];
        float4 NB0 = nB[0], NB1 = nB[64], NB2 = nB[128], NB3 = nB[192];

        // row A (identical FP order to previous version)
        float sap = 0.f, san = 0.f;
        acc8(A0, PA0, NA0, sap, san); acc8(A1, PA1, NA1, sap, san);
        acc8(A2, PA2, NA2, sap, san); acc8(A3, PA3, NA3, sap, san);
        for (int off = 32; off; off >>= 1) {
            sap += __shfl_xor(sap, off, 64);
            san += __shfl_xor(san, off, 64);
        }
        if (lane == 0 && pnA.x >= 0 && pnA.y >= 0) {
            lsum += fmaxf(sqrtf(sap) - sqrtf(san) + MARGIN, 0.f);
            lcnt += 1.f;
        }

        // row B
        sap = 0.f; san = 0.f;
        acc8(B0, PB0, NB0, sap, san); acc8(B1, PB1, NB1, sap, san);
        acc8(B2, PB2, NB2, sap, san); acc8(B3, PB3, NB3, sap, san);
        for (int off = 32; off; off >>= 1) {
            sap += __shfl_xor(sap, off, 64);
            san += __shfl_xor(san, off, 64);
        }
        if (lane == 0 && pnB.x >= 0 && pnB.y >= 0) {
            lsum += fmaxf(sqrtf(sap) - sqrtf(san) + MARGIN, 0.f);
            lcnt += 1.f;
        }
    } else {
        if (hasA)
            row_generic(z, ia, pnA.x < 0 ? 0 : pnA.x, pnA.y < 0 ? 0 : pnA.y,
                        C, lane, lsum, lcnt, pnA.x >= 0 && pnA.y >= 0);
        if (hasB)
            row_generic(z, ib, pnB.x < 0 ? 0 : pnB.x, pnB.y < 0 ? 0 : pnB.y,
                        C, lane, lsum, lcnt, pnB.x >= 0 && pnB.y >= 0);
    }

    __shared__ float s_sum[4], s_cnt[4];
    if (lane == 0) { s_sum[wave] = lsum; s_cnt[wave] = lcnt; }
    __syncthreads();
    if (threadIdx.x == 0) {
        float bs = 0.f, bc = 0.f;
        for (int w = 0; w < 4; ++w) { bs += s_sum[w]; bc += s_cnt[w]; }
        g_part[blockIdx.x] = make_float2(bs, bc);
    }
}

// -------- Kernel 2: reduce partials, write loss (unchanged, bit-exact) ------
__global__ __launch_bounds__(1024) void final_kernel(
    const float2* __restrict__ g_part, int nb, float* __restrict__ out)
{
    const int t = threadIdx.x;
    float s = 0.f, c = 0.f;
    for (int idx = t; idx < nb; idx += blockDim.x) {
        float2 v = g_part[idx];
        s += v.x; c += v.y;
    }
    for (int off = 32; off; off >>= 1) {
        s += __shfl_xor(s, off, 64);
        c += __shfl_xor(c, off, 64);
    }
    __shared__ float s_s[16], s_c[16];
    const int wave = t >> 6, lane = t & 63;
    if (lane == 0) { s_s[wave] = s; s_c[wave] = c; }
    __syncthreads();
    if (t == 0) {
        float ts = 0.f, tc = 0.f;
        const int nw = blockDim.x >> 6;
        for (int w = 0; w < nw; ++w) { ts += s_s[w]; tc += s_c[w]; }
        out[0] = (tc > 0.f) ? ts / tc : 0.f;
    }
}

extern "C" void kernel_launch(void* const* d_in, const int* in_sizes, int n_in,
                              void* d_out, int out_size, void* d_ws, size_t ws_size,
                              hipStream_t stream) {
    const int*   z_label = (const int*)d_in[0];
    const int*   z_idx   = (const int*)d_in[1];
    const float* z       = (const float*)d_in[2];
    const int B = in_sizes[0];
    const int C = in_sizes[2] / B;
    float* out = (float*)d_out;

    const int nblk = (B + 7) / 8;       // 2 rows per wave, 4 waves/block
    float2* g_part = (float2*)d_ws;
    size_t pn_off = ((size_t)nblk * sizeof(float2) + 255) & ~(size_t)255;
    int2* pn = (int2*)((char*)d_ws + pn_off);

    mine_kernel<<<(B + 3) / 4, 256, 0, stream>>>(z_label, z_idx, B, pn);
    dist_kernel<<<nblk, 256, 0, stream>>>(z, pn, B, C, g_part);
    final_kernel<<<1, 1024, 0, stream>>>(g_part, nblk, out);
}